// Round 8
// baseline (1437.153 us; speedup 1.0000x reference)
//
#include <hip/hip_runtime.h>
#include <math.h>

// Shapes: B=32, C=256, H=W=64 (HW=4096), ch=64, ac=384
// h buffer lives in d_out.
// ws: xt_pad (32x64 planes of 64 rows x 68 cols; image col x -> padded col x+2;
// cols 0,1,66,67 are zero -> conv needs NO x-edge masking and window = two
// aligned float4 loads) + temp[5 ops] (41.9M f) + stats.
// Pads zeroed once per launch via hipMemsetAsync; k_scale rewrites interiors.

#define PLANE 4352   // 64*68 floats per (b,ch) plane
#define PCOLS 68

__device__ __forceinline__ float wave_sum(float v){
#pragma unroll
    for (int o = 32; o; o >>= 1) v += __shfl_down(v, o, 64);
    return v;
}
__device__ __forceinline__ float wave_max(float v){
#pragma unroll
    for (int o = 32; o; o >>= 1) v = fmaxf(v, __shfl_down(v, o, 64));
    return v;
}

// K1: per-(b,c) spatial mean & max of relu(src)
__global__ __launch_bounds__(256) void k_meanmax(const float* __restrict__ src,
                                                 float* __restrict__ meanb,
                                                 float* __restrict__ maxb){
    int bc = blockIdx.x, t = threadIdx.x;
    const float4* p = (const float4*)(src + ((size_t)bc << 12));
    float s = 0.f, m = 0.f;
    for (int i = t; i < 1024; i += 256){
        float4 v = p[i];
        float a = fmaxf(v.x, 0.f), b = fmaxf(v.y, 0.f), c = fmaxf(v.z, 0.f), d = fmaxf(v.w, 0.f);
        s += (a + b) + (c + d);
        m = fmaxf(m, fmaxf(fmaxf(a, b), fmaxf(c, d)));
    }
    s = wave_sum(s); m = wave_max(m);
    __shared__ float ss[4], sm_[4];
    int lane = t & 63, w = t >> 6;
    if (!lane){ ss[w] = s; sm_[w] = m; }
    __syncthreads();
    if (!t){
        meanb[bc] = (ss[0] + ss[1] + ss[2] + ss[3]) * (1.f / 4096.f);
        maxb[bc]  = fmaxf(fmaxf(sm_[0], sm_[1]), fmaxf(sm_[2], sm_[3]));
    }
}

// K2: nl = sigmoid(mlp(mean)+mlp(max)); w1:(128,256), w2:(256,128)
__global__ __launch_bounds__(256) void k_nl(const float* __restrict__ meanb, const float* __restrict__ maxb,
                                            const float* __restrict__ w1, const float* __restrict__ w2,
                                            float* __restrict__ nl){
    int b = blockIdx.x, t = threadIdx.x;
    __shared__ float sm[256], sx[256], hid[128];
    sm[t] = meanb[b * 256 + t]; sx[t] = maxb[b * 256 + t];
    __syncthreads();
    if (t < 128){
        float a = 0.f, c = 0.f;
        const float* wr = w1 + t * 256;
        for (int k = 0; k < 256; ++k){ float w = wr[k]; a = fmaf(w, sm[k], a); c = fmaf(w, sx[k], c); }
        hid[t] = fmaxf(a, 0.f) + fmaxf(c, 0.f);   // relu(h_mean)+relu(h_max), second matmul is linear
    }
    __syncthreads();
    float o = 0.f;
    const float* wr = w2 + t * 128;
    for (int j = 0; j < 128; ++j) o = fmaf(wr[j], hid[j], o);
    nl[b * 256 + t] = 1.f / (1.f + expf(-o));
}

// K2b: slist = nl.sum(0); stable top-64; also zeros the conv zero-row buffer
__global__ __launch_bounds__(256) void k_topk(const float* __restrict__ nl,
                                              int* __restrict__ idx, int* __restrict__ selpos,
                                              float* __restrict__ zpad){
    int t = threadIdx.x;
    if (t < 128) zpad[t] = 0.f;
    __shared__ float sl[256];
    float s = 0.f;
    for (int b = 0; b < 32; ++b) s += nl[b * 256 + t];
    sl[t] = s; __syncthreads();
    float mys = sl[t];
    int rank = 0;
    for (int c = 0; c < 256; ++c){ float v = sl[c]; rank += (v > mys) || (v == mys && c < t); }
    selpos[t] = (rank < 64) ? rank : -1;
    if (rank < 64) idx[rank] = t;
}

// K3: dst = relu(src)*nl (all 256 ch); gather selected channels into padded planes
__global__ __launch_bounds__(256) void k_scale(const float* __restrict__ src, float* __restrict__ dst,
                                               float* __restrict__ xtp, const float* __restrict__ nl,
                                               const int* __restrict__ selpos){
    int bc = blockIdx.x, t = threadIdx.x;
    int b = bc >> 8, c = bc & 255;
    float sc = nl[bc];
    int sp = selpos[c];
    const float4* s4 = (const float4*)(src + ((size_t)bc << 12));
    float4* d4 = (float4*)(dst + ((size_t)bc << 12));
    float* xp = (sp >= 0) ? (xtp + (size_t)(b * 64 + sp) * PLANE) : (float*)nullptr;
    for (int i = t; i < 1024; i += 256){
        float4 v = s4[i];
        v.x = fmaxf(v.x, 0.f) * sc; v.y = fmaxf(v.y, 0.f) * sc;
        v.z = fmaxf(v.z, 0.f) * sc; v.w = fmaxf(v.w, 0.f) * sc;
        d4[i] = v;
        if (sp >= 0){
            float* w = xp + (i >> 4) * PCOLS + ((i & 15) << 2) + 2;   // 8B-aligned
            *(float2*)(w)     = make_float2(v.x, v.y);
            *(float2*)(w + 2) = make_float2(v.z, v.w);
        }
    }
}

// K4a/K4b: LDS-free direct conv on padded planes. Per (ic,dy): TWO aligned
// float4 loads (padded cols 4k..4k+7) -> window v[0..7]; no x-edge cndmask
// (pad cols are zero), only a row-OOB pointer select (2 cndmask). r7 evidence:
// boundary masking + 3-load addressing was 40% of VALU issue (574K vs 409K
// cyc/SIMD); this cuts non-FMA VALU to ~6%.
#define OCB5 8
__global__ __launch_bounds__(256, 4) void k_conv5(const float* __restrict__ xtp,
                                                  const float* __restrict__ w5,
                                                  const float* __restrict__ zpad,
                                                  float* __restrict__ temp){
    int t = threadIdx.x;
    int k = t & 15, ty = t >> 4;
    int tile = blockIdx.x;        // 0..3
    int oc0 = blockIdx.y * OCB5;  // 0..56
    int b = blockIdx.z;
    int y = (tile << 4) + ty;     // 0..63
    const float* zrow = zpad + (k << 2);

    float a5[OCB5][4];
#pragma unroll
    for (int o = 0; o < OCB5; ++o)
#pragma unroll
        for (int px = 0; px < 4; ++px) a5[o][px] = 0.f;

    const float* plane = xtp + (size_t)(b * 64) * PLANE + (k << 2);
    for (int ic = 0; ic < 64; ++ic, plane += PLANE){
#pragma unroll
        for (int dy = 0; dy < 5; ++dy){
            int gy = y - 2 + dy;
            const float* rp = ((unsigned)gy < 64u) ? (plane + gy * PCOLS) : zrow;
            float4 A  = *(const float4*)(rp);
            float4 Bv = *(const float4*)(rp + 4);
            float v[8] = {A.x, A.y, A.z, A.w, Bv.x, Bv.y, Bv.z, Bv.w};
#pragma unroll
            for (int o = 0; o < OCB5; ++o){
                const float* W5r = w5 + (size_t)((oc0 + o) * 64 + ic) * 25 + dy * 5;
                float w50 = W5r[0], w51 = W5r[1], w52 = W5r[2], w53 = W5r[3], w54 = W5r[4];
#pragma unroll
                for (int px = 0; px < 4; ++px){
                    float acc = a5[o][px];
                    acc = fmaf(v[px + 0], w50, acc);
                    acc = fmaf(v[px + 1], w51, acc);
                    acc = fmaf(v[px + 2], w52, acc);
                    acc = fmaf(v[px + 3], w53, acc);
                    acc = fmaf(v[px + 4], w54, acc);
                    a5[o][px] = acc;
                }
            }
        }
    }

    size_t pix = ((size_t)y << 6) + (k << 2);
    size_t bb = (size_t)b * 320;
#pragma unroll
    for (int o = 0; o < OCB5; ++o){
        int oc = oc0 + o;
        *(float4*)(temp + (((bb + 128 + oc) << 12) + pix)) = make_float4(a5[o][0], a5[o][1], a5[o][2], a5[o][3]);
    }
}

#define OCB3 4
__global__ __launch_bounds__(256, 4) void k_conv31(const float* __restrict__ xtp,
                                                   const float* __restrict__ w1,
                                                   const float* __restrict__ w3,
                                                   const float* __restrict__ zpad,
                                                   float* __restrict__ temp){
    int t = threadIdx.x;
    int k = t & 15, ty = t >> 4;
    int tile = blockIdx.x;        // 0..3
    int oc0 = blockIdx.y * OCB3;  // 0..60
    int b = blockIdx.z;
    int y = (tile << 4) + ty;
    const float* zrow = zpad + (k << 2);

    float a1[OCB3][4], a3[OCB3][4];
#pragma unroll
    for (int o = 0; o < OCB3; ++o)
#pragma unroll
        for (int px = 0; px < 4; ++px){ a1[o][px] = 0.f; a3[o][px] = 0.f; }

    const float* plane = xtp + (size_t)(b * 64) * PLANE + (k << 2);
    for (int ic = 0; ic < 64; ++ic, plane += PLANE){
#pragma unroll
        for (int dy = 0; dy < 3; ++dy){
            int gy = y - 1 + dy;
            const float* rp = ((unsigned)gy < 64u) ? (plane + gy * PCOLS) : zrow;
            float4 A  = *(const float4*)(rp);
            float4 Bv = *(const float4*)(rp + 4);
            float v[8] = {A.x, A.y, A.z, A.w, Bv.x, Bv.y, Bv.z, Bv.w};
#pragma unroll
            for (int o = 0; o < OCB3; ++o){
                const float* W3r = w3 + (size_t)((oc0 + o) * 64 + ic) * 9 + dy * 3;
                float w30 = W3r[0], w31 = W3r[1], w32 = W3r[2];
#pragma unroll
                for (int px = 0; px < 4; ++px){
                    float acc = a3[o][px];
                    acc = fmaf(v[px + 1], w30, acc);
                    acc = fmaf(v[px + 2], w31, acc);
                    acc = fmaf(v[px + 3], w32, acc);
                    a3[o][px] = acc;
                }
            }
            if (dy == 1){
#pragma unroll
                for (int o = 0; o < OCB3; ++o){
                    float w10 = w1[(oc0 + o) * 64 + ic];
#pragma unroll
                    for (int px = 0; px < 4; ++px)
                        a1[o][px] = fmaf(v[px + 2], w10, a1[o][px]);
                }
            }
        }
    }

    size_t pix = ((size_t)y << 6) + (k << 2);
    size_t bb = (size_t)b * 320;
#pragma unroll
    for (int o = 0; o < OCB3; ++o){
        int oc = oc0 + o;
        *(float4*)(temp + (((bb + oc) << 12) + pix))      = make_float4(a1[o][0], a1[o][1], a1[o][2], a1[o][3]);
        *(float4*)(temp + (((bb + 64 + oc) << 12) + pix)) = make_float4(a3[o][0], a3[o][1], a3[o][2], a3[o][3]);
    }
}

// K5: 3x3 avg (count-normalized) + max pool from padded planes (x always in
// bounds: padded col = tx0+cc+1 in [1,66]; pads are zero = OOB semantics)
__global__ __launch_bounds__(256) void k_pool(const float* __restrict__ xtp, float* __restrict__ temp){
    __shared__ float sm[18][18];
    int t = threadIdx.x;
    int tx = t & 15, ty = t >> 4;
    int tile = blockIdx.x, c = blockIdx.y, b = blockIdx.z;
    int ty0 = (tile >> 2) * 16, tx0 = (tile & 3) * 16;
    const float* plane = xtp + (size_t)(b * 64 + c) * PLANE;
    for (int i = t; i < 324; i += 256){
        int r = i / 18, cc = i - r * 18;
        int gy = ty0 - 1 + r;
        sm[r][cc] = ((unsigned)gy < 64u) ? plane[gy * PCOLS + tx0 + cc + 1] : 0.f;
    }
    __syncthreads();
    float s = 0.f, m = 0.f;
#pragma unroll
    for (int ky = 0; ky < 3; ++ky)
#pragma unroll
        for (int kx = 0; kx < 3; ++kx){ float v = sm[ty + ky][tx + kx]; s += v; m = fmaxf(m, v); }
    int y = ty0 + ty, x = tx0 + tx;
    int cy = min(y + 1, 63) - max(y - 1, 0) + 1;
    int cx = min(x + 1, 63) - max(x - 1, 0) + 1;
    size_t pix = ((size_t)y << 6) + x;
    size_t bb = (size_t)b * 320;
    temp[((bb + 192 + c) << 12) + pix] = s / (float)(cy * cx);
    temp[((bb + 256 + c) << 12) + pix] = m;
}

// K6: spatial sums of all 384 concat channels. op5 sums the whole padded
// plane (pads are zero -> sum unchanged), 1088 aligned float4s.
__global__ __launch_bounds__(256) void k_smean(const float* __restrict__ temp, const float* __restrict__ xtp,
                                               float* __restrict__ tsum){
    int opc = blockIdx.x, b = blockIdx.y, t = threadIdx.x;
    float s = 0.f;
    if (opc < 320){
        const float4* p = (const float4*)(temp + (((size_t)b * 320 + opc) << 12));
        for (int i = t; i < 1024; i += 256){ float4 v = p[i]; s += (v.x + v.y) + (v.z + v.w); }
    } else {
        const float4* p = (const float4*)(xtp + (size_t)(b * 64 + (opc - 320)) * PLANE);
        for (int i = t; i < 1088; i += 256){ float4 v = p[i]; s += (v.x + v.y) + (v.z + v.w); }
    }
    s = wave_sum(s);
    __shared__ float ss[4];
    int lane = t & 63, w = t >> 6;
    if (!lane) ss[w] = s;
    __syncthreads();
    if (!t) tsum[b * 384 + opc] = ss[0] + ss[1] + ss[2] + ss[3];
}

// K6b: BN stats (mean, rsqrt(var+eps)) over (B,H,W) for the 128 pool channels
__global__ __launch_bounds__(256) void k_bnstats(const float* __restrict__ temp,
                                                 float* __restrict__ bn_m, float* __restrict__ bn_r){
    int q = blockIdx.x, t = threadIdx.x;     // q: 0..127 -> op=3+q/64, c=q%64
    int opc = 192 + q;                        // channel offset within b*320 block
    float s = 0.f, s2 = 0.f;
    for (int b = 0; b < 32; ++b){
        const float4* p = (const float4*)(temp + (((size_t)b * 320 + opc) << 12));
        for (int i = t; i < 1024; i += 256){
            float4 v = p[i];
            s += (v.x + v.y) + (v.z + v.w);
            s2 = fmaf(v.x, v.x, s2); s2 = fmaf(v.y, v.y, s2);
            s2 = fmaf(v.z, v.z, s2); s2 = fmaf(v.w, v.w, s2);
        }
    }
    s = wave_sum(s); s2 = wave_sum(s2);
    __shared__ float ss[4], ss2[4];
    int lane = t & 63, w = t >> 6;
    if (!lane){ ss[w] = s; ss2[w] = s2; }
    __syncthreads();
    if (!t){
        float S = ss[0] + ss[1] + ss[2] + ss[3], S2 = ss2[0] + ss2[1] + ss2[2] + ss2[3];
        const float N = 131072.f;
        float m = S / N;
        float var = S2 / N - m * m;
        bn_m[q] = m;
        bn_r[q] = rsqrtf(var + 1e-5f);
    }
}

// K7: y = sigmoid(relu(tm @ w1.T) @ w2.T); tm adjusts ops3/4 by BN. w1:(48,384), w2:(384,48)
__global__ __launch_bounds__(384) void k_att(const float* __restrict__ tsum, const float* __restrict__ bn_m,
                                             const float* __restrict__ bn_r,
                                             const float* __restrict__ w1, const float* __restrict__ w2,
                                             float* __restrict__ yv){
    int b = blockIdx.x, t = threadIdx.x;
    __shared__ float tm[384], hid[48];
    float v = tsum[b * 384 + t] * (1.f / 4096.f);
    if (t >= 192 && t < 320){ int q = t - 192; v = (v - bn_m[q]) * bn_r[q]; }
    tm[t] = v; __syncthreads();
    if (t < 48){
        float a = 0.f; const float* wr = w1 + t * 384;
        for (int k = 0; k < 384; ++k) a = fmaf(wr[k], tm[k], a);
        hid[t] = fmaxf(a, 0.f);
    }
    __syncthreads();
    float o = 0.f; const float* wr = w2 + t * 48;
    for (int j = 0; j < 48; ++j) o = fmaf(wr[j], hid[j], o);
    yv[b * 384 + t] = 1.f / (1.f + expf(-o));
}

// K8: out = sum_op y_op * op_val (BN folded); scatter to h[:, idx[c]].
// op5 read from padded plane via two 8B-aligned float2 loads.
__global__ __launch_bounds__(256) void k_combine(const float* __restrict__ temp, const float* __restrict__ xtp,
                                                 const float* __restrict__ yv, const float* __restrict__ bn_m,
                                                 const float* __restrict__ bn_r, const int* __restrict__ idxp,
                                                 float* __restrict__ h){
    int c = blockIdx.x, b = blockIdx.y, t = threadIdx.x;
    const float* yb = yv + b * 384;
    float y0 = yb[c], y1 = yb[64 + c], y2 = yb[128 + c];
    float y3 = yb[192 + c], y4 = yb[256 + c], y5 = yb[320 + c];
    float m3 = bn_m[c], r3 = bn_r[c], m4 = bn_m[64 + c], r4 = bn_r[64 + c];
    float a3 = y3 * r3, c3 = -y3 * r3 * m3, a4 = y4 * r4, c4 = -y4 * r4 * m4;
    float bias = c3 + c4;
    size_t base = (((size_t)b * 320 + c) << 12);
    const float4* t0 = (const float4*)(temp + base);
    const float4* t1 = (const float4*)(temp + base + (64ull << 12));
    const float4* t2 = (const float4*)(temp + base + (128ull << 12));
    const float4* t3 = (const float4*)(temp + base + (192ull << 12));
    const float4* t4 = (const float4*)(temp + base + (256ull << 12));
    const float* p5 = xtp + (size_t)(b * 64 + c) * PLANE;
    float4* o4 = (float4*)(h + (((size_t)(b * 256 + idxp[c])) << 12));
    for (int i = t; i < 1024; i += 256){
        float4 v0 = t0[i], v1 = t1[i], v2 = t2[i], v3 = t3[i], v4 = t4[i];
        const float* r5 = p5 + (i >> 4) * PCOLS + ((i & 15) << 2) + 2;
        float2 lo = *(const float2*)(r5);
        float2 hi = *(const float2*)(r5 + 2);
        float4 r;
        r.x = y0 * v0.x + y1 * v1.x + y2 * v2.x + a3 * v3.x + a4 * v4.x + y5 * lo.x + bias;
        r.y = y0 * v0.y + y1 * v1.y + y2 * v2.y + a3 * v3.y + a4 * v4.y + y5 * lo.y + bias;
        r.z = y0 * v0.z + y1 * v1.z + y2 * v2.z + a3 * v3.z + a4 * v4.z + y5 * hi.x + bias;
        r.w = y0 * v0.w + y1 * v1.w + y2 * v2.w + a3 * v3.w + a4 * v4.w + y5 * hi.y + bias;
        o4[i] = r;
    }
}

// K9: d_out += x
__global__ __launch_bounds__(256) void k_addx(const float* __restrict__ x, float* __restrict__ out){
    const float4* x4 = (const float4*)x;
    float4* o4 = (float4*)out;
    for (int i = blockIdx.x * 256 + threadIdx.x; i < 8388608; i += 8192 * 256){
        float4 a = x4[i], b = o4[i];
        b.x += a.x; b.y += a.y; b.z += a.z; b.w += a.w;
        o4[i] = b;
    }
}

extern "C" void kernel_launch(void* const* d_in, const int* in_sizes, int n_in,
                              void* d_out, int out_size, void* d_ws, size_t ws_size,
                              hipStream_t stream){
    const float* x = (const float*)d_in[0];
    float* h = (float*)d_out;                 // h buffer lives in d_out
    float* ws = (float*)d_ws;
    float* xtp   = ws;                        // 32*64*4352 = 8,912,896 floats (padded planes)
    float* temp  = ws + 8912896;              // 41,943,040 floats (5 ops)
    float* small = ws + 8912896 + 41943040;
    float* meanb = small;                     // 8192
    float* maxb  = small + 8192;              // 8192
    float* nl    = small + 16384;             // 8192
    float* tsum  = small + 24576;             // 12288
    float* bn_m  = small + 36864;             // 128
    float* bn_r  = small + 36992;             // 128
    float* yv    = small + 37120;             // 12288
    int*   idxp  = (int*)(small + 49408);     // 64
    int*   selp  = idxp + 64;                 // 256
    float* zpad  = small + 49792;             // 128 floats, zeroed by k_topk

    // zero padded planes once (pads stay zero; interiors rewritten by k_scale)
    hipMemsetAsync(xtp, 0, 8912896ull * 4, stream);

    for (int r = 0; r < 2; ++r){
        const float* ca_w1 = (const float*)d_in[2 + r * 7];
        const float* ca_w2 = (const float*)d_in[3 + r * 7];
        const float* w1    = (const float*)d_in[4 + r * 7];
        const float* w3    = (const float*)d_in[5 + r * 7];
        const float* w5    = (const float*)d_in[6 + r * 7];
        const float* a_w1  = (const float*)d_in[7 + r * 7];
        const float* a_w2  = (const float*)d_in[8 + r * 7];
        const float* src = (r == 0) ? x : h;

        hipLaunchKernelGGL(k_meanmax, dim3(8192), dim3(256), 0, stream, src, meanb, maxb);
        hipLaunchKernelGGL(k_nl,      dim3(32),   dim3(256), 0, stream, meanb, maxb, ca_w1, ca_w2, nl);
        hipLaunchKernelGGL(k_topk,    dim3(1),    dim3(256), 0, stream, nl, idxp, selp, zpad);
        hipLaunchKernelGGL(k_scale,   dim3(8192), dim3(256), 0, stream, src, h, xtp, nl, selp);
        hipLaunchKernelGGL(k_conv5,   dim3(4, 8, 32),   dim3(256), 0, stream, xtp, w5, zpad, temp);
        hipLaunchKernelGGL(k_conv31,  dim3(4, 16, 32),  dim3(256), 0, stream, xtp, w1, w3, zpad, temp);
        hipLaunchKernelGGL(k_pool,    dim3(16, 64, 32), dim3(256), 0, stream, xtp, temp);
        hipLaunchKernelGGL(k_smean,   dim3(384, 32),    dim3(256), 0, stream, temp, xtp, tsum);
        hipLaunchKernelGGL(k_bnstats, dim3(128),  dim3(256), 0, stream, temp, bn_m, bn_r);
        hipLaunchKernelGGL(k_att,     dim3(32),   dim3(384), 0, stream, tsum, bn_m, bn_r, a_w1, a_w2, yv);
        hipLaunchKernelGGL(k_combine, dim3(64, 32), dim3(256), 0, stream, temp, xtp, yv, bn_m, bn_r, idxp, h);
    }
    hipLaunchKernelGGL(k_addx, dim3(8192), dim3(256), 0, stream, x, h);
}